// Round 2
// baseline (227.772 us; speedup 1.0000x reference)
//
#include <hip/hip_runtime.h>
#include <hip/hip_bf16.h>
#include <math.h>

#define J 75
#define EDGES 300
#define MAXE (EDGES + J)
#define HID 64
#define OUTF 256
#define BT 2048
#define MTOT (BT * J)              // 153600 rows, tight
#define K2_BM 128
#define K2_BLOCKS (MTOT / K2_BM)   // 1200
#define BSPW 66           // Bsp row width in uints (64 + 2 pad -> 2-way banks max)
#define BSPROWS 96        // k rows padded to 3 K-chunks of 32
#define CSTR2 72          // (fallback kernel only)

typedef __attribute__((ext_vector_type(8))) short short8;
typedef __attribute__((ext_vector_type(4))) float f32x4;

__device__ __forceinline__ unsigned short f32_to_bf16_rn(float f) {
    unsigned u = __float_as_uint(f);
    unsigned r = u + 0x7FFFu + ((u >> 16) & 1u);
    return (unsigned short)(r >> 16);
}
__device__ __forceinline__ float bf16_to_f32(unsigned short h) {
    return __uint_as_float(((unsigned)h) << 16);
}
// tanh-form gelu: max |err| vs exact-erf gelu ~3e-4
__device__ __forceinline__ float gelu_fast(float v) {
    float v2 = v * v;
    float t  = fmaf(v2, 0.044715f, 1.0f);
    float z  = 0.7978845608028654f * v * t;        // gelu = v * sigmoid(2z)
    float e  = __expf(2.0f * z);
    float r  = __builtin_amdgcn_rcpf(e + 1.0f);
    return v * (1.0f - r);
}

// ---------------- Kernel 0: prep ----------------
// blocks 0..63: W2 -> MFMA B-frag order, split bf16 hi/lo
// block 64:     CSR (for x-aggregation)
// block 65:     dense Ahat -> MFMA A-frag order, split bf16 hi/lo
__global__ void prep_kernel(const int* __restrict__ ei,
                            const float* __restrict__ W2,
                            int* __restrict__ csr_off,
                            unsigned short* __restrict__ csr_src,
                            float* __restrict__ csr_norm,
                            unsigned short* __restrict__ Whi,
                            unsigned short* __restrict__ Wlo,
                            unsigned short* __restrict__ Ahi,
                            unsigned short* __restrict__ Alo) {
    const int tid = threadIdx.x;

    if (blockIdx.x < 64) {
        // B[k][n]: k = kc*32 + quad*8 + j, n = nt*16 + l16; linear t = ((kc*16+nt)*64+lane)*8+j
        int t = blockIdx.x * 256 + tid;
        int j    = t & 7;
        int lane = (t >> 3) & 63;
        int nt   = (t >> 9) & 15;
        int kc   = t >> 13;
        int k = kc * 32 + (lane >> 4) * 8 + j;
        int n = nt * 16 + (lane & 15);
        float w = W2[k * OUTF + n];
        unsigned short hi = f32_to_bf16_rn(w);
        Whi[t] = hi;
        Wlo[t] = f32_to_bf16_rn(w - bf16_to_f32(hi));
        return;
    }

    if (blockIdx.x == 64) {
        __shared__ int   deg[J];
        __shared__ int   off[J + 1];
        __shared__ int   cur[J];
        __shared__ float dis[J];
        if (tid < J) { deg[tid] = 1; cur[tid] = 0; }
        __syncthreads();
        for (int e = tid; e < EDGES; e += 256) atomicAdd(&deg[ei[EDGES + e]], 1);
        __syncthreads();
        if (tid == 0) {
            int s = 0;
            for (int j = 0; j < J; ++j) { off[j] = s; s += deg[j]; }
            off[J] = s;
        }
        if (tid < J) dis[tid] = rsqrtf((float)deg[tid]);
        __syncthreads();
        for (int e = tid; e < EDGES; e += 256) {
            int s = ei[e], d = ei[EDGES + e];
            int p = off[d] + atomicAdd(&cur[d], 1);
            csr_src[p]  = (unsigned short)s;
            csr_norm[p] = dis[s] * dis[d];
        }
        for (int j = tid; j < J; j += 256) {
            int p = off[j] + atomicAdd(&cur[j], 1);
            csr_src[p]  = (unsigned short)j;
            csr_norm[p] = dis[j] * dis[j];
        }
        __syncthreads();
        for (int j = tid; j <= J; j += 256) csr_off[j] = off[j];
        return;
    }

    // ---- block 65: dense Ahat[80][96] (zero-padded), then emit A-frags hi/lo ----
    __shared__ float Ad[80 * 96];
    __shared__ int   deg2[J];
    __shared__ float dis2[J];
    for (int i = tid; i < 80 * 96; i += 256) Ad[i] = 0.f;
    if (tid < J) deg2[tid] = 1;
    __syncthreads();
    for (int e = tid; e < EDGES; e += 256) atomicAdd(&deg2[ei[EDGES + e]], 1);
    __syncthreads();
    if (tid < J) dis2[tid] = rsqrtf((float)deg2[tid]);
    __syncthreads();
    for (int e = tid; e < EDGES; e += 256) {
        int s = ei[e], d = ei[EDGES + e];
        atomicAdd(&Ad[d * 96 + s], dis2[s] * dis2[d]);   // multi-edges accumulate
    }
    __syncthreads();
    if (tid < J) Ad[tid * 96 + tid] += dis2[tid] * dis2[tid];  // self loop
    __syncthreads();
    // emit 15 frags (mt 0..4, kc 0..2): A[m][k], m = mt*16+l16, k = kc*32+quad*8+jj
    for (int t = tid; t < 15 * 512; t += 256) {
        int jj   = t & 7;
        int lane = (t >> 3) & 63;
        int f    = t >> 9;               // mt*3 + kc
        int mt = f / 3, kc = f - mt * 3;
        int m = mt * 16 + (lane & 15);
        int k = kc * 32 + (lane >> 4) * 8 + jj;
        float v = Ad[m * 96 + k];
        unsigned short hi = f32_to_bf16_rn(v);
        Ahi[t] = hi;
        Alo[t] = f32_to_bf16_rn(v - bf16_to_f32(hi));
    }
}

// ---------------- Kernel 1: per-(b,t) layer-1 + aggregation, emit packed C plane ----------------
// C = Ahat @ gelu((Ahat@x)@W1 + b1), stored as packed uint (bf16 hi | lo<<16), [MTOT][64].
__global__ void __launch_bounds__(256, 4) gcn_l1_kernel(
        const float* __restrict__ xg,
        const float* __restrict__ W1,
        const float* __restrict__ b1,
        const int*   __restrict__ csr_off,
        const unsigned short* __restrict__ csr_src,
        const float* __restrict__ csr_norm,
        const unsigned short* __restrict__ Ahi,
        const unsigned short* __restrict__ Alo,
        unsigned int* __restrict__ Cp) {
    __shared__ __align__(16) unsigned int Bsp[BSPROWS * BSPW];   // 25344 B
    __shared__ float xs[J * 3];
    __shared__ float ax[J * 3];
    __shared__ float W1s[3 * HID];
    __shared__ float b1s[HID];
    __shared__ int   offs[J + 1];
    __shared__ unsigned short srcs[MAXE];
    __shared__ float nrms[MAXE];

    const int tid  = threadIdx.x;
    const int bt   = blockIdx.x;
    const int wv   = tid >> 6;
    const int lane = tid & 63;
    const int quad = lane >> 4;
    const int l16  = lane & 15;

    // ---- stage ----
    if (tid < J + 1) offs[tid] = csr_off[tid];
    for (int i = tid; i < MAXE; i += 256) { srcs[i] = csr_src[i]; nrms[i] = csr_norm[i]; }
    if (tid < 3 * HID) W1s[tid] = W1[tid];
    if (tid < HID)     b1s[tid] = b1[tid];
    for (int i = tid; i < J * 3; i += 256) xs[i] = xg[bt * (J * 3) + i];
    __syncthreads();

    // ---- aggregate x (75 x 3, VALU gather — tiny) ----
    for (int idx = tid; idx < J * 3; idx += 256) {
        int j = idx / 3, d = idx - j * 3;
        float s = 0.f;
        int p0 = offs[j], p1 = offs[j + 1];
        for (int p = p0; p < p1; ++p) s += nrms[p] * xs[srcs[p] * 3 + d];
        ax[idx] = s;
    }
    __syncthreads();

    // ---- layer 1: (3->64) + gelu, write into Bsp as bf16 hi/lo packed ----
    for (int idx = tid; idx < J * HID; idx += 256) {
        int j = idx >> 6, f = idx & 63;
        float v = ax[j * 3 + 0] * W1s[0 * HID + f]
                + ax[j * 3 + 1] * W1s[1 * HID + f]
                + ax[j * 3 + 2] * W1s[2 * HID + f]
                + b1s[f];
        float g = gelu_fast(v);
        unsigned short hi = f32_to_bf16_rn(g);
        unsigned short lo = f32_to_bf16_rn(g - bf16_to_f32(hi));
        Bsp[j * BSPW + f] = (unsigned)hi | ((unsigned)lo << 16);
    }
    // zero pad rows 75..95 (avoid NaN garbage under 0*x in MFMA)
    for (int idx = tid; idx < (BSPROWS - J) * BSPW; idx += 256) {
        int r = J + idx / BSPW, c = idx - (idx / BSPW) * BSPW;
        Bsp[r * BSPW + c] = 0u;
    }
    __syncthreads();

    // ---- aggregation via MFMA: C(80x64) = Ahat(80x96) @ B(96x64), split-bf16 3-MFMA ----
    // wave wv owns feature n-tile wv (cols wv*16 .. wv*16+15)
    f32x4 cacc[5] = {};
    const short8* Ahi8 = (const short8*)Ahi;
    const short8* Alo8 = (const short8*)Alo;
#pragma unroll
    for (int kc = 0; kc < 3; ++kc) {
        unsigned w[8];
#pragma unroll
        for (int jj = 0; jj < 8; ++jj)
            w[jj] = Bsp[(kc * 32 + quad * 8 + jj) * BSPW + wv * 16 + l16];
        short8 bh, bl;
#pragma unroll
        for (int jj = 0; jj < 8; ++jj) {
            bh[jj] = (short)(w[jj] & 0xFFFFu);
            bl[jj] = (short)(w[jj] >> 16);
        }
#pragma unroll
        for (int mt = 0; mt < 5; ++mt) {
            short8 ah = Ahi8[(mt * 3 + kc) * 64 + lane];   // L2-resident, coalesced
            short8 al = Alo8[(mt * 3 + kc) * 64 + lane];
            cacc[mt] = __builtin_amdgcn_mfma_f32_16x16x32_bf16(ah, bh, cacc[mt], 0, 0, 0);
            cacc[mt] = __builtin_amdgcn_mfma_f32_16x16x32_bf16(ah, bl, cacc[mt], 0, 0, 0);
            cacc[mt] = __builtin_amdgcn_mfma_f32_16x16x32_bf16(al, bh, cacc[mt], 0, 0, 0);
        }
    }

    // ---- emit packed C plane (tight rows: only row < J): 4 B/lane stores ----
    const int col = wv * 16 + l16;
#pragma unroll
    for (int mt = 0; mt < 5; ++mt) {
#pragma unroll
        for (int r = 0; r < 4; ++r) {
            int row = mt * 16 + quad * 4 + r;      // C/D: row=quad*4+reg, col=l16
            if (row < J) {
                float v = cacc[mt][r];
                unsigned short hi = f32_to_bf16_rn(v);
                unsigned short lo = f32_to_bf16_rn(v - bf16_to_f32(hi));
                Cp[(size_t)(bt * J + row) * HID + col] = (unsigned)hi | ((unsigned)lo << 16);
            }
        }
    }
}

// ---------------- Kernel 2: streaming GEMM out = gelu(C @ W2 + b2) ----------------
// M = 153600 (tight), K = 64, N = 256. No LDS, no barriers. 128 rows/block, 1200 blocks.
// Wave wv owns cols wv*64..wv*64+63 (4 n-tiles) — single pass, C read ONCE, all W in regs.
__global__ void __launch_bounds__(256, 4) gcn_l2_kernel(
        const unsigned int* __restrict__ Cp,
        const unsigned short* __restrict__ Whi,
        const unsigned short* __restrict__ Wlo,
        const float* __restrict__ b2,
        float* __restrict__ outg) {
    const int tid  = threadIdx.x;
    const int wv   = tid >> 6;
    const int lane = tid & 63;
    const int quad = lane >> 4;
    const int l16  = lane & 15;
    const int m0   = blockIdx.x * K2_BM;

    const short8* Whi8 = (const short8*)Whi;
    const short8* Wlo8 = (const short8*)Wlo;

    // All W2 frags for this wave's 4 n-tiles: [kc][nt], hi+lo = 16 frags = 64 VGPR
    short8 wh[2][4], wl[2][4];
    float  b2v[4];
#pragma unroll
    for (int kc = 0; kc < 2; ++kc)
#pragma unroll
        for (int q = 0; q < 4; ++q) {
            int nt = wv * 4 + q;
            int fi = (kc * 16 + nt) * 64 + lane;
            wh[kc][q] = Whi8[fi];
            wl[kc][q] = Wlo8[fi];
        }
#pragma unroll
    for (int q = 0; q < 4; ++q) b2v[q] = b2[(wv * 4 + q) * 16 + l16];

#pragma unroll 1
    for (int mt = 0; mt < 8; ++mt) {
        const int row = m0 + mt * 16 + l16;
        // A-frag source: packed uints C[row][kc*32 + quad*8 .. +7]
        const uint4* cr = (const uint4*)(Cp + (size_t)row * HID) + quad * 2;

        f32x4 acc[4];
#pragma unroll
        for (int q = 0; q < 4; ++q) acc[q] = (f32x4){b2v[q], b2v[q], b2v[q], b2v[q]};

#pragma unroll
        for (int kc = 0; kc < 2; ++kc) {
            uint4 w0 = cr[kc * 8 + 0];
            uint4 w1 = cr[kc * 8 + 1];
            unsigned cw[8] = {w0.x, w0.y, w0.z, w0.w, w1.x, w1.y, w1.z, w1.w};
            short8 ah, al;
#pragma unroll
            for (int j = 0; j < 8; ++j) {
                ah[j] = (short)(cw[j] & 0xFFFFu);
                al[j] = (short)(cw[j] >> 16);
            }
#pragma unroll
            for (int q = 0; q < 4; ++q) {
                acc[q] = __builtin_amdgcn_mfma_f32_16x16x32_bf16(ah, wh[kc][q], acc[q], 0, 0, 0);
                acc[q] = __builtin_amdgcn_mfma_f32_16x16x32_bf16(ah, wl[kc][q], acc[q], 0, 0, 0);
                acc[q] = __builtin_amdgcn_mfma_f32_16x16x32_bf16(al, wh[kc][q], acc[q], 0, 0, 0);
            }
        }

        // epilogue: gelu + store (every row valid — tight M)
#pragma unroll
        for (int q = 0; q < 4; ++q) {
            int o = (wv * 4 + q) * 16 + l16;
#pragma unroll
            for (int r = 0; r < 4; ++r) {
                int orow = m0 + mt * 16 + quad * 4 + r;
                outg[(size_t)orow * OUTF + o] = gelu_fast(acc[q][r]);
            }
        }
    }
}

// ---------------- Fallback: previous verified fused kernel (used if ws too small) ----------------
__global__ void __launch_bounds__(256, 4) gcn_fused_kernel(
        const float* __restrict__ xg,
        const float* __restrict__ W1,
        const float* __restrict__ b1,
        const float* __restrict__ b2,
        const int*   __restrict__ csr_off,
        const unsigned short* __restrict__ csr_src,
        const float* __restrict__ csr_norm,
        const unsigned short* __restrict__ Whi,
        const unsigned short* __restrict__ Wlo,
        const unsigned short* __restrict__ Ahi,
        const unsigned short* __restrict__ Alo,
        float* __restrict__ outg) {
    __shared__ __align__(16) unsigned int Ubuf[BSPROWS * BSPW];
    __shared__ float xs[J * 3];
    __shared__ float ax[J * 3];
    __shared__ float W1s[3 * HID];
    __shared__ float b1s[HID];
    __shared__ float b2s[OUTF];
    __shared__ int   offs[J + 1];
    __shared__ unsigned short srcs[MAXE];
    __shared__ float nrms[MAXE];

    const int tid  = threadIdx.x;
    const int bt   = blockIdx.x;
    const int wv   = tid >> 6;
    const int lane = tid & 63;
    const int quad = lane >> 4;
    const int l16  = lane & 15;

    if (tid < J + 1) offs[tid] = csr_off[tid];
    for (int i = tid; i < MAXE; i += 256) { srcs[i] = csr_src[i]; nrms[i] = csr_norm[i]; }
    if (tid < 3 * HID) W1s[tid] = W1[tid];
    if (tid < HID)     b1s[tid] = b1[tid];
    if (tid < OUTF)    b2s[tid] = b2[tid];
    for (int i = tid; i < J * 3; i += 256) xs[i] = xg[bt * (J * 3) + i];
    __syncthreads();

    for (int idx = tid; idx < J * 3; idx += 256) {
        int j = idx / 3, d = idx - j * 3;
        float s = 0.f;
        int p0 = offs[j], p1 = offs[j + 1];
        for (int p = p0; p < p1; ++p) s += nrms[p] * xs[srcs[p] * 3 + d];
        ax[idx] = s;
    }
    __syncthreads();

    for (int idx = tid; idx < J * HID; idx += 256) {
        int j = idx >> 6, f = idx & 63;
        float v = ax[j * 3 + 0] * W1s[0 * HID + f]
                + ax[j * 3 + 1] * W1s[1 * HID + f]
                + ax[j * 3 + 2] * W1s[2 * HID + f]
                + b1s[f];
        float g = gelu_fast(v);
        unsigned short hi = f32_to_bf16_rn(g);
        unsigned short lo = f32_to_bf16_rn(g - bf16_to_f32(hi));
        Ubuf[j * BSPW + f] = (unsigned)hi | ((unsigned)lo << 16);
    }
    for (int idx = tid; idx < (BSPROWS - J) * BSPW; idx += 256) {
        int r = J + idx / BSPW, c = idx - (idx / BSPW) * BSPW;
        Ubuf[r * BSPW + c] = 0u;
    }
    __syncthreads();

    f32x4 cacc[5] = {};
    const short8* Ahi8 = (const short8*)Ahi;
    const short8* Alo8 = (const short8*)Alo;
#pragma unroll
    for (int kc = 0; kc < 3; ++kc) {
        unsigned w[8];
#pragma unroll
        for (int jj = 0; jj < 8; ++jj)
            w[jj] = Ubuf[(kc * 32 + quad * 8 + jj) * BSPW + wv * 16 + l16];
        short8 bh, bl;
#pragma unroll
        for (int jj = 0; jj < 8; ++jj) {
            bh[jj] = (short)(w[jj] & 0xFFFFu);
            bl[jj] = (short)(w[jj] >> 16);
        }
#pragma unroll
        for (int mt = 0; mt < 5; ++mt) {
            short8 ah = Ahi8[(mt * 3 + kc) * 64 + lane];
            short8 al = Alo8[(mt * 3 + kc) * 64 + lane];
            cacc[mt] = __builtin_amdgcn_mfma_f32_16x16x32_bf16(ah, bh, cacc[mt], 0, 0, 0);
            cacc[mt] = __builtin_amdgcn_mfma_f32_16x16x32_bf16(ah, bl, cacc[mt], 0, 0, 0);
            cacc[mt] = __builtin_amdgcn_mfma_f32_16x16x32_bf16(al, bh, cacc[mt], 0, 0, 0);
        }
    }
    __syncthreads();

    unsigned short* CH = (unsigned short*)Ubuf;
    unsigned short* CL = CH + 80 * CSTR2;
#pragma unroll
    for (int mt = 0; mt < 5; ++mt) {
#pragma unroll
        for (int r = 0; r < 4; ++r) {
            int node = mt * 16 + quad * 4 + r;
            int feat = wv * 16 + l16;
            float v = cacc[mt][r];
            unsigned short hi = f32_to_bf16_rn(v);
            unsigned short lo = f32_to_bf16_rn(v - bf16_to_f32(hi));
            CH[node * CSTR2 + feat] = hi;
            CL[node * CSTR2 + feat] = lo;
        }
    }
    __syncthreads();

    const short8* Whi8 = (const short8*)Whi;
    const short8* Wlo8 = (const short8*)Wlo;
    float* outb = outg + (size_t)bt * (J * OUTF);

#pragma unroll
    for (int p = 0; p < 2; ++p) {
        f32x4 acc[5][2];
#pragma unroll
        for (int q2 = 0; q2 < 2; ++q2) {
            int nt2 = wv * 4 + p * 2 + q2;
            float bv = b2s[nt2 * 16 + l16];
#pragma unroll
            for (int mt = 0; mt < 5; ++mt) acc[mt][q2] = (f32x4){bv, bv, bv, bv};
        }
#pragma unroll
        for (int kc = 0; kc < 2; ++kc) {
            short8 wh[2], wl[2];
#pragma unroll
            for (int q2 = 0; q2 < 2; ++q2) {
                int nt2 = wv * 4 + p * 2 + q2;
                int fi = (kc * 16 + nt2) * 64 + lane;
                wh[q2] = Whi8[fi];
                wl[q2] = Wlo8[fi];
            }
#pragma unroll
            for (int mt = 0; mt < 5; ++mt) {
                const unsigned short* ab = &CH[(mt * 16 + l16) * CSTR2 + kc * 32 + quad * 8];
                short8 ah = *(const short8*)ab;
                short8 al = *(const short8*)(ab + 80 * CSTR2);
#pragma unroll
                for (int q2 = 0; q2 < 2; ++q2) {
                    acc[mt][q2] = __builtin_amdgcn_mfma_f32_16x16x32_bf16(ah, wh[q2], acc[mt][q2], 0, 0, 0);
                    acc[mt][q2] = __builtin_amdgcn_mfma_f32_16x16x32_bf16(ah, wl[q2], acc[mt][q2], 0, 0, 0);
                    acc[mt][q2] = __builtin_amdgcn_mfma_f32_16x16x32_bf16(al, wh[q2], acc[mt][q2], 0, 0, 0);
                }
            }
        }
#pragma unroll
        for (int mt = 0; mt < 5; ++mt) {
#pragma unroll
            for (int q2 = 0; q2 < 2; ++q2) {
                int o = (wv * 4 + p * 2 + q2) * 16 + l16;
#pragma unroll
                for (int r = 0; r < 4; ++r) {
                    int row = mt * 16 + quad * 4 + r;
                    if (row < J)
                        outb[row * OUTF + o] = gelu_fast(acc[mt][q2][r]);
                }
            }
        }
    }
}

extern "C" void kernel_launch(void* const* d_in, const int* in_sizes, int n_in,
                              void* d_out, int out_size, void* d_ws, size_t ws_size,
                              hipStream_t stream) {
    const float* x  = (const float*)d_in[0];
    const int*   ei = (const int*)d_in[1];
    const float* W1 = (const float*)d_in[2];
    const float* b1 = (const float*)d_in[3];
    const float* W2 = (const float*)d_in[4];
    const float* b2 = (const float*)d_in[5];
    float* out = (float*)d_out;

    char* ws = (char*)d_ws;
    int*            csr_off  = (int*)ws;                          // 304 B
    unsigned short* csr_src  = (unsigned short*)(ws + 512);       // 750 B
    float*          csr_norm = (float*)(ws + 2048);               // 1500 B
    unsigned short* Whi      = (unsigned short*)(ws + 4096);      // 32 KB
    unsigned short* Wlo      = (unsigned short*)(ws + 36864);     // 32 KB
    unsigned short* Ahi      = (unsigned short*)(ws + 69632);     // 15360 B
    unsigned short* Alo      = (unsigned short*)(ws + 86016);     // 15360 B
    // Packed C plane: uint (bf16 hi | lo<<16), [MTOT][64] = 39,321,600 B
    unsigned int*   Cp       = (unsigned int*)(ws + 102400);
    const size_t CPLANE = (size_t)MTOT * HID * sizeof(unsigned int);
    const size_t need = 102400 + CPLANE;                          // ~39.4 MB

    prep_kernel<<<66, 256, 0, stream>>>(ei, W2, csr_off, csr_src, csr_norm,
                                        Whi, Wlo, Ahi, Alo);
    if (ws_size >= need) {
        gcn_l1_kernel<<<BT, 256, 0, stream>>>(x, W1, b1,
                                              csr_off, csr_src, csr_norm,
                                              Ahi, Alo, Cp);
        gcn_l2_kernel<<<K2_BLOCKS, 256, 0, stream>>>(Cp, Whi, Wlo, b2, out);
    } else {
        gcn_fused_kernel<<<BT, 256, 0, stream>>>(x, W1, b1, b2,
                                                 csr_off, csr_src, csr_norm,
                                                 Whi, Wlo, Ahi, Alo, out);
    }
}

// Round 3
// 210.376 us; speedup vs baseline: 1.0827x; 1.0827x over previous
//
#include <hip/hip_runtime.h>
#include <hip/hip_bf16.h>
#include <math.h>

#define J 75
#define EDGES 300
#define MAXE (EDGES + J)
#define HID 64
#define OUTF 256
#define BT 2048
#define BSPW 66           // Bsp row width in uints (64 + 2 pad -> 2-way banks max)
#define BSPROWS 96        // k rows padded to 3 K-chunks of 32
#define CSTR2 72          // Csp plane row stride in ushorts (144B: 16B-aligned, 2-way banks)

typedef __attribute__((ext_vector_type(8))) short short8;
typedef __attribute__((ext_vector_type(4))) float f32x4;

__device__ __forceinline__ unsigned short f32_to_bf16_rn(float f) {
    unsigned u = __float_as_uint(f);
    unsigned r = u + 0x7FFFu + ((u >> 16) & 1u);
    return (unsigned short)(r >> 16);
}
__device__ __forceinline__ float bf16_to_f32(unsigned short h) {
    return __uint_as_float(((unsigned)h) << 16);
}
// tanh-form gelu: max |err| vs exact-erf gelu ~3e-4
__device__ __forceinline__ float gelu_fast(float v) {
    float v2 = v * v;
    float t  = fmaf(v2, 0.044715f, 1.0f);
    float z  = 0.7978845608028654f * v * t;        // gelu = v * sigmoid(2z)
    float e  = __expf(2.0f * z);
    float r  = __builtin_amdgcn_rcpf(e + 1.0f);
    return v * (1.0f - r);
}

// ---------------- Kernel 0: prep ----------------
// blocks 0..63: W2 -> MFMA B-frag order, split bf16 hi/lo
// block 64:     CSR (for x-aggregation)
// block 65:     dense Ahat -> MFMA A-frag order, split bf16 hi/lo
__global__ void prep_kernel(const int* __restrict__ ei,
                            const float* __restrict__ W2,
                            int* __restrict__ csr_off,
                            unsigned short* __restrict__ csr_src,
                            float* __restrict__ csr_norm,
                            unsigned short* __restrict__ Whi,
                            unsigned short* __restrict__ Wlo,
                            unsigned short* __restrict__ Ahi,
                            unsigned short* __restrict__ Alo) {
    const int tid = threadIdx.x;

    if (blockIdx.x < 64) {
        // B[k][n]: k = kc*32 + quad*8 + j, n = nt*16 + l16; linear t = ((kc*16+nt)*64+lane)*8+j
        int t = blockIdx.x * 256 + tid;
        int j    = t & 7;
        int lane = (t >> 3) & 63;
        int nt   = (t >> 9) & 15;
        int kc   = t >> 13;
        int k = kc * 32 + (lane >> 4) * 8 + j;
        int n = nt * 16 + (lane & 15);
        float w = W2[k * OUTF + n];
        unsigned short hi = f32_to_bf16_rn(w);
        Whi[t] = hi;
        Wlo[t] = f32_to_bf16_rn(w - bf16_to_f32(hi));
        return;
    }

    if (blockIdx.x == 64) {
        __shared__ int   deg[J];
        __shared__ int   off[J + 1];
        __shared__ int   cur[J];
        __shared__ float dis[J];
        if (tid < J) { deg[tid] = 1; cur[tid] = 0; }
        __syncthreads();
        for (int e = tid; e < EDGES; e += 256) atomicAdd(&deg[ei[EDGES + e]], 1);
        __syncthreads();
        if (tid == 0) {
            int s = 0;
            for (int j = 0; j < J; ++j) { off[j] = s; s += deg[j]; }
            off[J] = s;
        }
        if (tid < J) dis[tid] = rsqrtf((float)deg[tid]);
        __syncthreads();
        for (int e = tid; e < EDGES; e += 256) {
            int s = ei[e], d = ei[EDGES + e];
            int p = off[d] + atomicAdd(&cur[d], 1);
            csr_src[p]  = (unsigned short)s;
            csr_norm[p] = dis[s] * dis[d];
        }
        for (int j = tid; j < J; j += 256) {
            int p = off[j] + atomicAdd(&cur[j], 1);
            csr_src[p]  = (unsigned short)j;
            csr_norm[p] = dis[j] * dis[j];
        }
        __syncthreads();
        for (int j = tid; j <= J; j += 256) csr_off[j] = off[j];
        return;
    }

    // ---- block 65: dense Ahat[80][96] (zero-padded), then emit A-frags hi/lo ----
    __shared__ float Ad[80 * 96];
    __shared__ int   deg2[J];
    __shared__ float dis2[J];
    for (int i = tid; i < 80 * 96; i += 256) Ad[i] = 0.f;
    if (tid < J) deg2[tid] = 1;
    __syncthreads();
    for (int e = tid; e < EDGES; e += 256) atomicAdd(&deg2[ei[EDGES + e]], 1);
    __syncthreads();
    if (tid < J) dis2[tid] = rsqrtf((float)deg2[tid]);
    __syncthreads();
    for (int e = tid; e < EDGES; e += 256) {
        int s = ei[e], d = ei[EDGES + e];
        atomicAdd(&Ad[d * 96 + s], dis2[s] * dis2[d]);   // multi-edges accumulate
    }
    __syncthreads();
    if (tid < J) Ad[tid * 96 + tid] += dis2[tid] * dis2[tid];  // self loop
    __syncthreads();
    // emit 15 frags (mt 0..4, kc 0..2): A[m][k], m = mt*16+l16, k = kc*32+quad*8+jj
    for (int t = tid; t < 15 * 512; t += 256) {
        int jj   = t & 7;
        int lane = (t >> 3) & 63;
        int f    = t >> 9;               // mt*3 + kc
        int mt = f / 3, kc = f - mt * 3;
        int m = mt * 16 + (lane & 15);
        int k = kc * 32 + (lane >> 4) * 8 + jj;
        float v = Ad[m * 96 + k];
        unsigned short hi = f32_to_bf16_rn(v);
        Ahi[t] = hi;
        Alo[t] = f32_to_bf16_rn(v - bf16_to_f32(hi));
    }
}

// ---------------- Kernel 1: fused 2-layer GCN, one block per (b,t) ----------------
__global__ void __launch_bounds__(256, 4) gcn_fused_kernel(
        const float* __restrict__ xg,
        const float* __restrict__ W1,
        const float* __restrict__ b1,
        const float* __restrict__ b2,
        const int*   __restrict__ csr_off,
        const unsigned short* __restrict__ csr_src,
        const float* __restrict__ csr_norm,
        const unsigned short* __restrict__ Whi,
        const unsigned short* __restrict__ Wlo,
        const unsigned short* __restrict__ Ahi,
        const unsigned short* __restrict__ Alo,
        float* __restrict__ outg) {
    // Union buffer: phase 2-3 = Bsp (hi|lo<<16 packed uints [96][66]);
    // phase 4-5 = Csp hi/lo ushort planes [80][72] each.
    __shared__ __align__(16) unsigned int Ubuf[BSPROWS * BSPW];   // 25344 B
    __shared__ float xs[J * 3];
    __shared__ float ax[J * 3];
    __shared__ float W1s[3 * HID];
    __shared__ float b1s[HID];
    __shared__ float b2s[OUTF];
    __shared__ int   offs[J + 1];
    __shared__ unsigned short srcs[MAXE];
    __shared__ float nrms[MAXE];

    const int tid  = threadIdx.x;
    const int bt   = blockIdx.x;
    const int wv   = tid >> 6;
    const int lane = tid & 63;
    const int quad = lane >> 4;
    const int l16  = lane & 15;

    // ---- stage ----
    if (tid < J + 1) offs[tid] = csr_off[tid];
    for (int i = tid; i < MAXE; i += 256) { srcs[i] = csr_src[i]; nrms[i] = csr_norm[i]; }
    if (tid < 3 * HID) W1s[tid] = W1[tid];
    if (tid < HID)     b1s[tid] = b1[tid];
    if (tid < OUTF)    b2s[tid] = b2[tid];
    for (int i = tid; i < J * 3; i += 256) xs[i] = xg[bt * (J * 3) + i];
    __syncthreads();

    // ---- aggregate x (75 x 3, VALU gather — tiny) ----
    for (int idx = tid; idx < J * 3; idx += 256) {
        int j = idx / 3, d = idx - j * 3;
        float s = 0.f;
        int p0 = offs[j], p1 = offs[j + 1];
        for (int p = p0; p < p1; ++p) s += nrms[p] * xs[srcs[p] * 3 + d];
        ax[idx] = s;
    }
    __syncthreads();

    // ---- layer 1: (3->64) + gelu, write straight into Bsp as bf16 hi/lo ----
    for (int idx = tid; idx < J * HID; idx += 256) {
        int j = idx >> 6, f = idx & 63;
        float v = ax[j * 3 + 0] * W1s[0 * HID + f]
                + ax[j * 3 + 1] * W1s[1 * HID + f]
                + ax[j * 3 + 2] * W1s[2 * HID + f]
                + b1s[f];
        float g = gelu_fast(v);
        unsigned short hi = f32_to_bf16_rn(g);
        unsigned short lo = f32_to_bf16_rn(g - bf16_to_f32(hi));
        Ubuf[j * BSPW + f] = (unsigned)hi | ((unsigned)lo << 16);
    }
    // zero pad rows 75..95 (avoid NaN garbage under 0*x in MFMA)
    for (int idx = tid; idx < (BSPROWS - J) * BSPW; idx += 256) {
        int r = J + idx / BSPW, c = idx - (idx / BSPW) * BSPW;
        Ubuf[r * BSPW + c] = 0u;
    }
    __syncthreads();

    // ---- aggregation via MFMA: C(80x64) = Ahat(80x96) @ B(96x64), split-bf16 3-MFMA ----
    // wave wv owns feature n-tile wv (cols wv*16 .. wv*16+15)
    f32x4 cacc[5] = {};
    const short8* Ahi8 = (const short8*)Ahi;
    const short8* Alo8 = (const short8*)Alo;
#pragma unroll
    for (int kc = 0; kc < 3; ++kc) {
        unsigned w[8];
#pragma unroll
        for (int jj = 0; jj < 8; ++jj)
            w[jj] = Ubuf[(kc * 32 + quad * 8 + jj) * BSPW + wv * 16 + l16];
        short8 bh, bl;
#pragma unroll
        for (int jj = 0; jj < 8; ++jj) {
            bh[jj] = (short)(w[jj] & 0xFFFFu);
            bl[jj] = (short)(w[jj] >> 16);
        }
#pragma unroll
        for (int mt = 0; mt < 5; ++mt) {
            short8 ah = Ahi8[(mt * 3 + kc) * 64 + lane];   // L2-resident, coalesced
            short8 al = Alo8[(mt * 3 + kc) * 64 + lane];
            cacc[mt] = __builtin_amdgcn_mfma_f32_16x16x32_bf16(ah, bh, cacc[mt], 0, 0, 0);
            cacc[mt] = __builtin_amdgcn_mfma_f32_16x16x32_bf16(ah, bl, cacc[mt], 0, 0, 0);
            cacc[mt] = __builtin_amdgcn_mfma_f32_16x16x32_bf16(al, bh, cacc[mt], 0, 0, 0);
        }
    }
    __syncthreads();   // all waves done reading Bsp before union is rewritten

    // ---- pack C into Csp hi/lo planes (A-frag friendly layout) ----
    unsigned short* CH = (unsigned short*)Ubuf;
    unsigned short* CL = CH + 80 * CSTR2;
#pragma unroll
    for (int mt = 0; mt < 5; ++mt) {
#pragma unroll
        for (int r = 0; r < 4; ++r) {
            int node = mt * 16 + quad * 4 + r;       // C/D: row=quad*4+reg, col=l16
            int feat = wv * 16 + l16;
            float v = cacc[mt][r];
            unsigned short hi = f32_to_bf16_rn(v);
            unsigned short lo = f32_to_bf16_rn(v - bf16_to_f32(hi));
            CH[node * CSTR2 + feat] = hi;
            CL[node * CSTR2 + feat] = lo;
        }
    }
    __syncthreads();

    // ---- layer 2: out(75x256) = C(75x64) @ W2(64x256), 2 passes x 2 n-tiles ----
    const short8* Whi8 = (const short8*)Whi;
    const short8* Wlo8 = (const short8*)Wlo;
    float* outb = outg + (size_t)bt * (J * OUTF);

#pragma unroll
    for (int p = 0; p < 2; ++p) {
        f32x4 acc[5][2];
#pragma unroll
        for (int q2 = 0; q2 < 2; ++q2) {
            int nt2 = wv * 4 + p * 2 + q2;
            float bv = b2s[nt2 * 16 + l16];
#pragma unroll
            for (int mt = 0; mt < 5; ++mt) acc[mt][q2] = (f32x4){bv, bv, bv, bv};
        }
#pragma unroll
        for (int kc = 0; kc < 2; ++kc) {
            short8 wh[2], wl[2];
#pragma unroll
            for (int q2 = 0; q2 < 2; ++q2) {
                int nt2 = wv * 4 + p * 2 + q2;
                int fi = (kc * 16 + nt2) * 64 + lane;
                wh[q2] = Whi8[fi];
                wl[q2] = Wlo8[fi];
            }
#pragma unroll
            for (int mt = 0; mt < 5; ++mt) {
                const unsigned short* ab = &CH[(mt * 16 + l16) * CSTR2 + kc * 32 + quad * 8];
                short8 ah = *(const short8*)ab;                       // ds_read_b128
                short8 al = *(const short8*)(ab + 80 * CSTR2);        // lo plane
#pragma unroll
                for (int q2 = 0; q2 < 2; ++q2) {
                    acc[mt][q2] = __builtin_amdgcn_mfma_f32_16x16x32_bf16(ah, wh[q2], acc[mt][q2], 0, 0, 0);
                    acc[mt][q2] = __builtin_amdgcn_mfma_f32_16x16x32_bf16(ah, wl[q2], acc[mt][q2], 0, 0, 0);
                    acc[mt][q2] = __builtin_amdgcn_mfma_f32_16x16x32_bf16(al, wh[q2], acc[mt][q2], 0, 0, 0);
                }
            }
        }
        // epilogue for this pass
#pragma unroll
        for (int mt = 0; mt < 5; ++mt) {
#pragma unroll
            for (int q2 = 0; q2 < 2; ++q2) {
                int o = (wv * 4 + p * 2 + q2) * 16 + l16;
#pragma unroll
                for (int r = 0; r < 4; ++r) {
                    int row = mt * 16 + quad * 4 + r;
                    if (row < J)
                        outb[row * OUTF + o] = gelu_fast(acc[mt][q2][r]);
                }
            }
        }
    }
}

extern "C" void kernel_launch(void* const* d_in, const int* in_sizes, int n_in,
                              void* d_out, int out_size, void* d_ws, size_t ws_size,
                              hipStream_t stream) {
    const float* x  = (const float*)d_in[0];
    const int*   ei = (const int*)d_in[1];
    const float* W1 = (const float*)d_in[2];
    const float* b1 = (const float*)d_in[3];
    const float* W2 = (const float*)d_in[4];
    const float* b2 = (const float*)d_in[5];
    float* out = (float*)d_out;

    char* ws = (char*)d_ws;
    int*            csr_off  = (int*)ws;                          // 304 B
    unsigned short* csr_src  = (unsigned short*)(ws + 512);       // 750 B
    float*          csr_norm = (float*)(ws + 2048);               // 1500 B
    unsigned short* Whi      = (unsigned short*)(ws + 4096);      // 32 KB
    unsigned short* Wlo      = (unsigned short*)(ws + 36864);     // 32 KB
    unsigned short* Ahi      = (unsigned short*)(ws + 69632);     // 15360 B
    unsigned short* Alo      = (unsigned short*)(ws + 86016);     // 15360 B

    prep_kernel<<<66, 256, 0, stream>>>(ei, W2, csr_off, csr_src, csr_norm,
                                        Whi, Wlo, Ahi, Alo);
    gcn_fused_kernel<<<BT, 256, 0, stream>>>(x, W1, b1, b2,
                                             csr_off, csr_src, csr_norm,
                                             Whi, Wlo, Ahi, Alo, out);
}